// Round 7
// baseline (113.452 us; speedup 1.0000x reference)
//
#include <hip/hip_runtime.h>
#include <math.h>

using short8   = __attribute__((ext_vector_type(8))) short;
using floatx4  = __attribute__((ext_vector_type(4))) float;
using ushort4v = __attribute__((ext_vector_type(4))) unsigned short;

__device__ __forceinline__ unsigned short f2bf(float x) {
  union { float f; unsigned u; } v; v.f = x;
  unsigned r = (v.u + 0x7FFFu + ((v.u >> 16) & 1u)) >> 16;
  return (unsigned short)r;
}
__device__ __forceinline__ float bf2f(unsigned short u) {
  union { unsigned u; float f; } v; v.u = ((unsigned)u) << 16;
  return v.f;
}

// ---------------- K0: pack adj int32 -> bit per element ----------------
// pk word index = global_int_index/32; bit p = adj[idx*32+p]
__global__ __launch_bounds__(256) void adj_pack(
    const int* __restrict__ adj, unsigned* __restrict__ pk) {
  size_t tid = (size_t)blockIdx.x * 256 + threadIdx.x;   // 0..1,048,575
  const int* src = adj + tid * 32;
  unsigned r = 0;
#pragma unroll
  for (int q = 0; q < 8; ++q) {
    int4 v = *(const int4*)(src + q * 4);
    r |= ((unsigned)v.x << (4 * q)) | ((unsigned)v.y << (4 * q + 1)) |
         ((unsigned)v.z << (4 * q + 2)) | ((unsigned)v.w << (4 * q + 3));
  }
  pk[tid] = r;
}

// ---------------- K1: Wh = h @ W  (f32 vector GEMM, bf16 output) ----------------
__global__ __launch_bounds__(256) void wh_gemm(
    const float* __restrict__ h, const float* __restrict__ W,
    unsigned short* __restrict__ Whb) {
  __shared__ __align__(16) float Al[16][64];
  __shared__ __align__(16) float Bl[16][128];
  const int m0 = blockIdx.x * 64;
  const int n0 = blockIdx.y * 128;
  const int t  = threadIdx.x;
  const int tx = t & 15, ty = t >> 4;
  float acc[4][8];
#pragma unroll
  for (int i = 0; i < 4; ++i)
#pragma unroll
    for (int j = 0; j < 8; ++j) acc[i][j] = 0.0f;

  for (int k0 = 0; k0 < 256; k0 += 16) {
    {
      int m = t & 63, kq = t >> 6;
      float4 v = *(const float4*)&h[(size_t)(m0 + m) * 256 + k0 + kq * 4];
      Al[kq * 4 + 0][m] = v.x; Al[kq * 4 + 1][m] = v.y;
      Al[kq * 4 + 2][m] = v.z; Al[kq * 4 + 3][m] = v.w;
    }
    {
      int n4 = t & 31, kr = t >> 5;
      *(float4*)&Bl[kr][n4 * 4]     = *(const float4*)&W[(size_t)(k0 + kr) * 256 + n0 + n4 * 4];
      *(float4*)&Bl[kr + 8][n4 * 4] = *(const float4*)&W[(size_t)(k0 + kr + 8) * 256 + n0 + n4 * 4];
    }
    __syncthreads();
#pragma unroll
    for (int k = 0; k < 16; ++k) {
      float4 av = *(const float4*)&Al[k][ty * 4];
      float4 b0 = *(const float4*)&Bl[k][tx * 4];
      float4 b1 = *(const float4*)&Bl[k][64 + tx * 4];
      float aa[4] = {av.x, av.y, av.z, av.w};
      float bb[8] = {b0.x, b0.y, b0.z, b0.w, b1.x, b1.y, b1.z, b1.w};
#pragma unroll
      for (int i = 0; i < 4; ++i)
#pragma unroll
        for (int j = 0; j < 8; ++j) acc[i][j] = fmaf(aa[i], bb[j], acc[i][j]);
    }
    __syncthreads();
  }
#pragma unroll
  for (int i = 0; i < 4; ++i) {
    size_t row = (size_t)(m0 + ty * 4 + i);
    ushort4v o0, o1;
#pragma unroll
    for (int j = 0; j < 4; ++j) { o0[j] = f2bf(acc[i][j]); o1[j] = f2bf(acc[i][4 + j]); }
    *(ushort4v*)&Whb[row * 256 + n0 + tx * 4]      = o0;
    *(ushort4v*)&Whb[row * 256 + n0 + 64 + tx * 4] = o1;
  }
}

// ---------------- K2a: g[row] = Wh[row,:] . a2 ----------------
__global__ __launch_bounds__(256) void g_rows(
    const unsigned short* __restrict__ Whb, const float* __restrict__ a,
    float* __restrict__ g) {
  int row = blockIdx.x * 4 + (threadIdx.x >> 6);
  int L = threadIdx.x & 63;
  ushort4v wv = *(const ushort4v*)&Whb[(size_t)row * 256 + L * 4];
  float4 av = *(const float4*)&a[256 + L * 4];
  float d = bf2f(wv[0]) * av.x + bf2f(wv[1]) * av.y + bf2f(wv[2]) * av.z + bf2f(wv[3]) * av.w;
#pragma unroll
  for (int off = 32; off > 0; off >>= 1) d += __shfl_xor(d, off);
  if (L == 0) g[row] = d;
}

// ---------------- K2b: per-batch max of g ----------------
__global__ __launch_bounds__(256) void batch_max(
    const float* __restrict__ g, float* __restrict__ Mb) {
  __shared__ float red[4];
  int b = blockIdx.x, t = threadIdx.x;
  float m = -1e30f;
  for (int i = t; i < 2048; i += 256) m = fmaxf(m, g[(size_t)b * 2048 + i]);
#pragma unroll
  for (int off = 32; off > 0; off >>= 1) m = fmaxf(m, __shfl_xor(m, off));
  if ((t & 63) == 0) red[t >> 6] = m;
  __syncthreads();
  if (t == 0) Mb[b] = fmaxf(fmaxf(red[0], red[1]), fmaxf(red[2], red[3]));
}

// ---------------- K2c: tile-contiguous B:
// Bt[((b*64 + kt)*320 + c)*64B], 64B = k-slots 0..3 (8 bf16 each) of s_j*Wh[b,j,c]
// (c==256 -> s_j; 257..319 -> 0)
__global__ __launch_bounds__(256) void build_bt(
    const unsigned short* __restrict__ Whb, const float* __restrict__ g,
    const float* __restrict__ Mb, unsigned short* __restrict__ Bt) {
  __shared__ __align__(16) unsigned short tile[320 * 64];  // [c][j]
  const int blk = blockIdx.x;
  const int b   = blk >> 5;
  const int j0  = (blk & 31) * 64;
  const int kt_base = (blk & 31) * 2;
  const int t   = threadIdx.x;
  const int j   = t & 63;
  const int q0  = t >> 6;
  const int row = b * 2048 + j0 + j;
  const float s = expf(g[row] - Mb[b]);
  for (int q = q0; q < 64; q += 4) {
    ushort4v wv = *(const ushort4v*)&Whb[(size_t)row * 256 + q * 4];
    int c = q * 4;
    tile[(c + 0) * 64 + j] = f2bf(s * bf2f(wv[0]));
    tile[(c + 1) * 64 + j] = f2bf(s * bf2f(wv[1]));
    tile[(c + 2) * 64 + j] = f2bf(s * bf2f(wv[2]));
    tile[(c + 3) * 64 + j] = f2bf(s * bf2f(wv[3]));
  }
  if (q0 == 0) tile[256 * 64 + j] = f2bf(s);
  for (int z = t; z < 63 * 64; z += 256) tile[257 * 64 + z] = 0;
  __syncthreads();
#pragma unroll
  for (int p = 0; p < 10; ++p) {
    int id = t + 256 * p;          // 0..2559 -> (c, off)
    int c = id >> 3, off = id & 7;
    int kt_l = off >> 2, slot = off & 3;
    size_t dst = ((size_t)((b * 64 + kt_base + kt_l) * 320 + c)) * 64 + (slot << 4);
    *(int4*)((char*)Bt + dst) = *(const int4*)&tile[c * 64 + off * 8];
  }
}

// ---------------- K3: [num|den] = adj @ Bt^T, barrier-free K-loop ----------------
// grid 256 (b=bid&7 XCD-pinned), 512 threads = 8 waves (2 row-grp x 4 col-grp).
// BM=64, BN=320. A = packed bits, whole strip (64 rows x 2048 bits = 16KB) staged
// to LDS once in prologue; K-loop has NO barriers, NO LDS writes. B direct
// global->reg, 4 named sets, 3-deep prefetch, compiler-managed waits.
__global__ __launch_bounds__(512) void gat_main(
    const unsigned* __restrict__ pk, const unsigned short* __restrict__ Bt,
    float* __restrict__ out) {
  __shared__ __align__(16) char lds[64 * 272 + 256];  // A bits (stride 272) + den
  const int bid = blockIdx.x;
  const int b   = bid & 7;
  const int rb  = bid >> 3;
  const int i0  = rb * 64;
  const int tid = threadIdx.x;
  const int w   = tid >> 6, L = tid & 63;
  const int wm  = w >> 2, wn = w & 3;     // row-group, col-group
  const int fr  = L & 15, kc = L >> 4;

  // prologue: stage 64 rows x 256B of packed bits, row stride 272
  {
    int r = tid >> 3, seg = tid & 7;
    const char* src = (const char*)pk + ((size_t)(b * 2048 + i0 + r) * 256 + seg * 32);
    char* dst = lds + r * 272 + seg * 32;
    *(int4*)(dst)      = *(const int4*)(src);
    *(int4*)(dst + 16) = *(const int4*)(src + 16);
  }
  __syncthreads();

  // B per-lane source: col = wn*80 + nf*16 + fr, k-slot kc
  const char* bsrc = (const char*)Bt + (size_t)b * 1310720
                   + (size_t)(wn * 80 + fr) * 64 + (kc << 4);
  const char* arow0 = lds + (wm * 32 + fr) * 272;        // mf=0 row
  const char* arow1 = arow0 + 16 * 272;                  // mf=1 row
  const int   ksh   = kc * 8;

  floatx4 acc[2][5];
#pragma unroll
  for (int i = 0; i < 2; ++i)
#pragma unroll
    for (int n = 0; n < 5; ++n) acc[i][n] = (floatx4)0.0f;

  short8 s0[5], s1[5], s2[5], s3[5];

#define LOADB(TT, SET) {                                  \
    const char* p_ = bsrc + (size_t)(TT) * 20480;         \
    SET[0] = *(const short8*)(p_);                        \
    SET[1] = *(const short8*)(p_ + 1024);                 \
    SET[2] = *(const short8*)(p_ + 2048);                 \
    SET[3] = *(const short8*)(p_ + 3072);                 \
    SET[4] = *(const short8*)(p_ + 4096);                 \
  }

  // bit->bf16 expand: y = x | x<<15; dword j = ((y>>2j) & 0x10001) * 0x3F80
#define AFRAG(AROW, TT, DST) {                            \
    unsigned word_ = *(const unsigned*)((AROW) + (TT) * 4); \
    unsigned x_ = (word_ >> ksh) & 0xFFu;                 \
    unsigned y_ = x_ | (x_ << 15);                        \
    union { unsigned u[4]; short8 s; } c_;                \
    c_.u[0] = (y_        & 0x10001u) * 0x3F80u;           \
    c_.u[1] = ((y_ >> 2) & 0x10001u) * 0x3F80u;           \
    c_.u[2] = ((y_ >> 4) & 0x10001u) * 0x3F80u;           \
    c_.u[3] = ((y_ >> 6) & 0x10001u) * 0x3F80u;           \
    DST = c_.s;                                           \
  }

#define COMPUTE(TT, SET) {                                                       \
    short8 af0_, af1_;                                                           \
    AFRAG(arow0, TT, af0_);                                                      \
    AFRAG(arow1, TT, af1_);                                                      \
    _Pragma("unroll")                                                            \
    for (int nf = 0; nf < 5; ++nf) {                                             \
      acc[0][nf] = __builtin_amdgcn_mfma_f32_16x16x32_bf16(af0_, SET[nf], acc[0][nf], 0, 0, 0); \
      acc[1][nf] = __builtin_amdgcn_mfma_f32_16x16x32_bf16(af1_, SET[nf], acc[1][nf], 0, 0, 0); \
    }                                                                            \
  }

  LOADB(0, s0); LOADB(1, s1); LOADB(2, s2);

#pragma unroll 1
  for (int k = 0; k < 15; ++k) {
    int t4 = k * 4;
    LOADB(t4 + 3, s3); COMPUTE(t4 + 0, s0);
    LOADB(t4 + 4, s0); COMPUTE(t4 + 1, s1);
    LOADB(t4 + 5, s1); COMPUTE(t4 + 2, s2);
    LOADB(t4 + 6, s2); COMPUTE(t4 + 3, s3);
  }
  // tail: s0=60, s1=61, s2=62
  LOADB(63, s3);
  COMPUTE(60, s0); COMPUTE(61, s1); COMPUTE(62, s2); COMPUTE(63, s3);

  // epilogue: den = col 256 -> wn==3, nf==1, fr==0
  float* denL = (float*)(lds + 64 * 272);
  const int q = L >> 4;
  if (wn == 3 && fr == 0) {
#pragma unroll
    for (int mf = 0; mf < 2; ++mf)
#pragma unroll
      for (int jj = 0; jj < 4; ++jj)
        denL[wm * 32 + mf * 16 + q * 4 + jj] = acc[mf][1][jj];
  }
  __syncthreads();
  float invd[2][4];
#pragma unroll
  for (int mf = 0; mf < 2; ++mf)
#pragma unroll
    for (int jj = 0; jj < 4; ++jj)
      invd[mf][jj] = 1.0f / denL[wm * 32 + mf * 16 + q * 4 + jj];
#pragma unroll
  for (int mf = 0; mf < 2; ++mf) {
#pragma unroll
    for (int nf = 0; nf < 5; ++nf) {
      int col = wn * 80 + nf * 16 + fr;
      if (col < 256) {
#pragma unroll
        for (int jj = 0; jj < 4; ++jj) {
          int row = wm * 32 + mf * 16 + q * 4 + jj;
          float v = acc[mf][nf][jj] * invd[mf][jj];
          v = (v > 0.0f) ? v : expm1f(v);
          out[((size_t)b * 2048 + i0 + row) * 256 + col] = v;
        }
      }
    }
  }
#undef COMPUTE
#undef AFRAG
#undef LOADB
}

extern "C" void kernel_launch(void* const* d_in, const int* in_sizes, int n_in,
                              void* d_out, int out_size, void* d_ws, size_t ws_size,
                              hipStream_t stream) {
  const float* h   = (const float*)d_in[0];
  const int*   adj = (const int*)d_in[1];
  const float* W   = (const float*)d_in[2];
  const float* a   = (const float*)d_in[3];
  float* out = (float*)d_out;

  char* ws = (char*)d_ws;
  if (ws_size < 23134464) return;
  unsigned short* Whb = (unsigned short*)ws;              //  8,388,608 B
  float* g            = (float*)(ws + 8388608);           //     65,536 B
  float* Mb           = (float*)(ws + 8454144);           //        256 B
  unsigned short* Bt  = (unsigned short*)(ws + 8454400);  // 10,485,760 B
  unsigned* pk        = (unsigned*)(ws + 18940160);       //  4,194,304 B

  adj_pack <<<4096,        256, 0, stream>>>(adj, pk);
  wh_gemm  <<<dim3(256, 2), 256, 0, stream>>>(h, W, Whb);
  g_rows   <<<4096,        256, 0, stream>>>(Whb, a, g);
  batch_max<<<8,           256, 0, stream>>>(g, Mb);
  build_bt <<<256,         256, 0, stream>>>(Whb, g, Mb, Bt);
  gat_main <<<256,         512, 0, stream>>>(pk, Bt, out);
}

// Round 8
// 103.238 us; speedup vs baseline: 1.0989x; 1.0989x over previous
//
#include <hip/hip_runtime.h>
#include <math.h>

using short8   = __attribute__((ext_vector_type(8))) short;
using floatx4  = __attribute__((ext_vector_type(4))) float;
using ushort4v = __attribute__((ext_vector_type(4))) unsigned short;

__device__ __forceinline__ unsigned short f2bf(float x) {
  union { float f; unsigned u; } v; v.f = x;
  unsigned r = (v.u + 0x7FFFu + ((v.u >> 16) & 1u)) >> 16;
  return (unsigned short)r;
}
__device__ __forceinline__ float bf2f(unsigned short u) {
  union { unsigned u; float f; } v; v.u = ((unsigned)u) << 16;
  return v.f;
}

// ---------------- K1: fused {wh_gemm + g-dot} (blocks 0..511) || adj_pack (512..4607)
__global__ __launch_bounds__(256) void pack_gemm(
    const int* __restrict__ adj, unsigned* __restrict__ pk,
    const float* __restrict__ h, const float* __restrict__ W,
    unsigned short* __restrict__ Whb, const float* __restrict__ a,
    float* __restrict__ g) {
  __shared__ __align__(16) float Al[16][64];
  __shared__ __align__(16) float Bl[16][128];

  if (blockIdx.x >= 512) {
    // ---- adj_pack: 4096 blocks, 1 word (32 adj ints) per thread ----
    size_t tid = (size_t)(blockIdx.x - 512) * 256 + threadIdx.x;  // 0..1,048,575
    const int* src = adj + tid * 32;
    unsigned r = 0;
#pragma unroll
    for (int q = 0; q < 8; ++q) {
      int4 v = *(const int4*)(src + q * 4);
      r |= ((unsigned)v.x << (4 * q)) | ((unsigned)v.y << (4 * q + 1)) |
           ((unsigned)v.z << (4 * q + 2)) | ((unsigned)v.w << (4 * q + 3));
    }
    pk[tid] = r;
    return;
  }

  // ---- wh_gemm: 512 blocks (m0 x n0 = 256 x 2), 64x128 f32 tile ----
  const int m0 = (blockIdx.x & 255) * 64;
  const int n0 = (blockIdx.x >> 8) * 128;
  const int t  = threadIdx.x;
  const int tx = t & 15, ty = t >> 4;
  float acc[4][8];
#pragma unroll
  for (int i = 0; i < 4; ++i)
#pragma unroll
    for (int j = 0; j < 8; ++j) acc[i][j] = 0.0f;

  for (int k0 = 0; k0 < 256; k0 += 16) {
    {
      int m = t & 63, kq = t >> 6;
      float4 v = *(const float4*)&h[(size_t)(m0 + m) * 256 + k0 + kq * 4];
      Al[kq * 4 + 0][m] = v.x; Al[kq * 4 + 1][m] = v.y;
      Al[kq * 4 + 2][m] = v.z; Al[kq * 4 + 3][m] = v.w;
    }
    {
      int n4 = t & 31, kr = t >> 5;
      *(float4*)&Bl[kr][n4 * 4]     = *(const float4*)&W[(size_t)(k0 + kr) * 256 + n0 + n4 * 4];
      *(float4*)&Bl[kr + 8][n4 * 4] = *(const float4*)&W[(size_t)(k0 + kr + 8) * 256 + n0 + n4 * 4];
    }
    __syncthreads();
#pragma unroll
    for (int k = 0; k < 16; ++k) {
      float4 av = *(const float4*)&Al[k][ty * 4];
      float4 b0 = *(const float4*)&Bl[k][tx * 4];
      float4 b1 = *(const float4*)&Bl[k][64 + tx * 4];
      float aa[4] = {av.x, av.y, av.z, av.w};
      float bb[8] = {b0.x, b0.y, b0.z, b0.w, b1.x, b1.y, b1.z, b1.w};
#pragma unroll
      for (int i = 0; i < 4; ++i)
#pragma unroll
        for (int j = 0; j < 8; ++j) acc[i][j] = fmaf(aa[i], bb[j], acc[i][j]);
    }
    __syncthreads();
  }
  // write Whb (bf16) + fused g-dot epilogue
  float4 a2lo = *(const float4*)&a[256 + n0 + tx * 4];
  float4 a2hi = *(const float4*)&a[256 + n0 + 64 + tx * 4];
#pragma unroll
  for (int i = 0; i < 4; ++i) {
    size_t row = (size_t)(m0 + ty * 4 + i);
    ushort4v o0, o1;
#pragma unroll
    for (int j = 0; j < 4; ++j) { o0[j] = f2bf(acc[i][j]); o1[j] = f2bf(acc[i][4 + j]); }
    *(ushort4v*)&Whb[row * 256 + n0 + tx * 4]      = o0;
    *(ushort4v*)&Whb[row * 256 + n0 + 64 + tx * 4] = o1;
    float p = acc[i][0] * a2lo.x + acc[i][1] * a2lo.y + acc[i][2] * a2lo.z + acc[i][3] * a2lo.w
            + acc[i][4] * a2hi.x + acc[i][5] * a2hi.y + acc[i][6] * a2hi.z + acc[i][7] * a2hi.w;
#pragma unroll
    for (int off = 1; off < 16; off <<= 1) p += __shfl_xor(p, off);
    if (tx == 0) atomicAdd(&g[row], p);
  }
}

// ---------------- K2b: per-batch max of g ----------------
__global__ __launch_bounds__(256) void batch_max(
    const float* __restrict__ g, float* __restrict__ Mb) {
  __shared__ float red[4];
  int b = blockIdx.x, t = threadIdx.x;
  float m = -1e30f;
  for (int i = t; i < 2048; i += 256) m = fmaxf(m, g[(size_t)b * 2048 + i]);
#pragma unroll
  for (int off = 32; off > 0; off >>= 1) m = fmaxf(m, __shfl_xor(m, off));
  if ((t & 63) == 0) red[t >> 6] = m;
  __syncthreads();
  if (t == 0) Mb[b] = fmaxf(fmaxf(red[0], red[1]), fmaxf(red[2], red[3]));
}

// ---------------- K2c: tile-contiguous B:
// Bt[((b*64 + kt)*320 + c)*64B], 64B = k-slots 0..3 (8 bf16 each) of s_j*Wh[b,j,c]
// (c==256 -> s_j; 257..319 -> 0)
__global__ __launch_bounds__(256) void build_bt(
    const unsigned short* __restrict__ Whb, const float* __restrict__ g,
    const float* __restrict__ Mb, unsigned short* __restrict__ Bt) {
  __shared__ __align__(16) unsigned short tile[320 * 64];  // [c][j]
  const int blk = blockIdx.x;
  const int b   = blk >> 5;
  const int j0  = (blk & 31) * 64;
  const int kt_base = (blk & 31) * 2;
  const int t   = threadIdx.x;
  const int j   = t & 63;
  const int q0  = t >> 6;
  const int row = b * 2048 + j0 + j;
  const float s = expf(g[row] - Mb[b]);
  for (int q = q0; q < 64; q += 4) {
    ushort4v wv = *(const ushort4v*)&Whb[(size_t)row * 256 + q * 4];
    int c = q * 4;
    tile[(c + 0) * 64 + j] = f2bf(s * bf2f(wv[0]));
    tile[(c + 1) * 64 + j] = f2bf(s * bf2f(wv[1]));
    tile[(c + 2) * 64 + j] = f2bf(s * bf2f(wv[2]));
    tile[(c + 3) * 64 + j] = f2bf(s * bf2f(wv[3]));
  }
  if (q0 == 0) tile[256 * 64 + j] = f2bf(s);
  for (int z = t; z < 63 * 64; z += 256) tile[257 * 64 + z] = 0;
  __syncthreads();
#pragma unroll
  for (int p = 0; p < 10; ++p) {
    int id = t + 256 * p;          // 0..2559 -> (c, off)
    int c = id >> 3, off = id & 7;
    int kt_l = off >> 2, slot = off & 3;
    size_t dst = ((size_t)((b * 64 + kt_base + kt_l) * 320 + c)) * 64 + (slot << 4);
    *(int4*)((char*)Bt + dst) = *(const int4*)&tile[c * 64 + off * 8];
  }
}

// ---------------- K3: [num|den] = adj @ Bt^T, barrier-free, 4-deep prefetch ----------------
// grid 256 (b=bid&7 XCD-pinned), 512 threads = 8 waves (2 row-grp x 4 col-grp).
// BM=64, BN=320. A = packed bits in LDS (staged once). B direct global->reg,
// 5 named sets, 4-deep prefetch, explicit vmcnt(20) gates. A-words prefetched
// one phase ahead into registers.
__global__ __launch_bounds__(512, 2) void gat_main(
    const unsigned* __restrict__ pk, const unsigned short* __restrict__ Bt,
    float* __restrict__ out) {
  __shared__ __align__(16) char lds[64 * 272 + 256];  // A bits (stride 272) + den
  const int bid = blockIdx.x;
  const int b   = bid & 7;
  const int rb  = bid >> 3;
  const int i0  = rb * 64;
  const int tid = threadIdx.x;
  const int w   = tid >> 6, L = tid & 63;
  const int wm  = w >> 2, wn = w & 3;     // row-group, col-group
  const int fr  = L & 15, kc = L >> 4;

  // prologue: stage 64 rows x 256B of packed bits, row stride 272
  {
    int r = tid >> 3, seg = tid & 7;
    const char* src = (const char*)pk + ((size_t)(b * 2048 + i0 + r) * 256 + seg * 32);
    char* dst = lds + r * 272 + seg * 32;
    *(int4*)(dst)      = *(const int4*)(src);
    *(int4*)(dst + 16) = *(const int4*)(src + 16);
  }
  __syncthreads();

  const char* bsrc = (const char*)Bt + (size_t)b * 1310720
                   + (size_t)(wn * 80 + fr) * 64 + (kc << 4);
  const char* arow0 = lds + (wm * 32 + fr) * 272;
  const char* arow1 = arow0 + 16 * 272;
  const int   ksh   = kc * 8;

  floatx4 acc[2][5];
#pragma unroll
  for (int i = 0; i < 2; ++i)
#pragma unroll
    for (int n = 0; n < 5; ++n) acc[i][n] = (floatx4)0.0f;

  short8 s0[5], s1[5], s2[5], s3[5], s4[5];

#define LOADB(TT, SET) {                                  \
    const char* p_ = bsrc + (size_t)(TT) * 20480;         \
    SET[0] = *(const short8*)(p_);                        \
    SET[1] = *(const short8*)(p_ + 1024);                 \
    SET[2] = *(const short8*)(p_ + 2048);                 \
    SET[3] = *(const short8*)(p_ + 3072);                 \
    SET[4] = *(const short8*)(p_ + 4096);                 \
  }

  // bit->bf16 expand: y = x | x<<15; dword j = ((y>>2j) & 0x10001) * 0x3F80
#define AFRAG(WORD, DST) {                                \
    unsigned x_ = ((WORD) >> ksh) & 0xFFu;                \
    unsigned y_ = x_ | (x_ << 15);                        \
    union { unsigned u[4]; short8 s; } c_;                \
    c_.u[0] = (y_        & 0x10001u) * 0x3F80u;           \
    c_.u[1] = ((y_ >> 2) & 0x10001u) * 0x3F80u;           \
    c_.u[2] = ((y_ >> 4) & 0x10001u) * 0x3F80u;           \
    c_.u[3] = ((y_ >> 6) & 0x10001u) * 0x3F80u;           \
    DST = c_.s;                                           \
  }

#define COMPUTE(W0, W1, SET) {                                                   \
    short8 af0_, af1_;                                                           \
    AFRAG(W0, af0_);                                                             \
    AFRAG(W1, af1_);                                                             \
    _Pragma("unroll")                                                            \
    for (int nf = 0; nf < 5; ++nf) {                                             \
      acc[0][nf] = __builtin_amdgcn_mfma_f32_16x16x32_bf16(af0_, SET[nf], acc[0][nf], 0, 0, 0); \
      acc[1][nf] = __builtin_amdgcn_mfma_f32_16x16x32_bf16(af1_, SET[nf], acc[1][nf], 0, 0, 0); \
    }                                                                            \
  }

  // steady-state phase: load tile TT+4, prefetch A-words for TT+1, gate, compute TT
#define PHASE(TT, CSET, LSET) {                                      \
    LOADB((TT) + 4, LSET);                                           \
    unsigned an0_ = *(const unsigned*)(arow0 + ((TT) + 1) * 4);      \
    unsigned an1_ = *(const unsigned*)(arow1 + ((TT) + 1) * 4);      \
    asm volatile("s_waitcnt vmcnt(20)" ::: "memory");                \
    COMPUTE(aw0, aw1, CSET);                                         \
    aw0 = an0_; aw1 = an1_;                                          \
  }

#define TAILPHASE(TT, GATE, CSET) {                                  \
    unsigned an0_ = *(const unsigned*)(arow0 + ((TT) + 1) * 4);      \
    unsigned an1_ = *(const unsigned*)(arow1 + ((TT) + 1) * 4);      \
    asm volatile("s_waitcnt vmcnt(" #GATE ")" ::: "memory");         \
    COMPUTE(aw0, aw1, CSET);                                         \
    aw0 = an0_; aw1 = an1_;                                          \
  }

  unsigned aw0 = *(const unsigned*)(arow0);
  unsigned aw1 = *(const unsigned*)(arow1);
  LOADB(0, s0); LOADB(1, s1); LOADB(2, s2); LOADB(3, s3);

#pragma unroll 1
  for (int k = 0; k < 12; ++k) {
    int t5 = k * 5;
    PHASE(t5 + 0, s0, s4);
    PHASE(t5 + 1, s1, s0);
    PHASE(t5 + 2, s2, s1);
    PHASE(t5 + 3, s3, s2);
    PHASE(t5 + 4, s4, s3);
  }
  // tiles 60..63 live in s0..s3 (T mod 5: 60->0, 61->1, 62->2, 63->3)
  TAILPHASE(60, 15, s0);
  TAILPHASE(61, 10, s1);
  TAILPHASE(62, 5,  s2);
  asm volatile("s_waitcnt vmcnt(0)" ::: "memory");
  COMPUTE(aw0, aw1, s3);

  // epilogue: den = col 256 -> wn==3, nf==1, fr==0
  float* denL = (float*)(lds + 64 * 272);
  const int q = L >> 4;
  if (wn == 3 && fr == 0) {
#pragma unroll
    for (int mf = 0; mf < 2; ++mf)
#pragma unroll
      for (int jj = 0; jj < 4; ++jj)
        denL[wm * 32 + mf * 16 + q * 4 + jj] = acc[mf][1][jj];
  }
  __syncthreads();
  float invd[2][4];
#pragma unroll
  for (int mf = 0; mf < 2; ++mf)
#pragma unroll
    for (int jj = 0; jj < 4; ++jj)
      invd[mf][jj] = 1.0f / denL[wm * 32 + mf * 16 + q * 4 + jj];
#pragma unroll
  for (int mf = 0; mf < 2; ++mf) {
#pragma unroll
    for (int nf = 0; nf < 5; ++nf) {
      int col = wn * 80 + nf * 16 + fr;
      if (col < 256) {
#pragma unroll
        for (int jj = 0; jj < 4; ++jj) {
          int row = wm * 32 + mf * 16 + q * 4 + jj;
          float v = acc[mf][nf][jj] * invd[mf][jj];
          v = (v > 0.0f) ? v : expm1f(v);
          out[((size_t)b * 2048 + i0 + row) * 256 + col] = v;
        }
      }
    }
  }
#undef PHASE
#undef TAILPHASE
#undef COMPUTE
#undef AFRAG
#undef LOADB
}

extern "C" void kernel_launch(void* const* d_in, const int* in_sizes, int n_in,
                              void* d_out, int out_size, void* d_ws, size_t ws_size,
                              hipStream_t stream) {
  const float* h   = (const float*)d_in[0];
  const int*   adj = (const int*)d_in[1];
  const float* W   = (const float*)d_in[2];
  const float* a   = (const float*)d_in[3];
  float* out = (float*)d_out;

  char* ws = (char*)d_ws;
  if (ws_size < 23134464) return;
  unsigned short* Whb = (unsigned short*)ws;              //  8,388,608 B
  float* g            = (float*)(ws + 8388608);           //     65,536 B
  float* Mb           = (float*)(ws + 8454144);           //        256 B
  unsigned short* Bt  = (unsigned short*)(ws + 8454400);  // 10,485,760 B
  unsigned* pk        = (unsigned*)(ws + 18940160);       //  4,194,304 B

  hipMemsetAsync(g, 0, 65536, stream);
  pack_gemm<<<4608,  256, 0, stream>>>(adj, pk, h, W, Whb, a, g);
  batch_max<<<8,     256, 0, stream>>>(g, Mb);
  build_bt <<<256,   256, 0, stream>>>(Whb, g, Mb, Bt);
  gat_main <<<256,   512, 0, stream>>>(pk, Bt, out);
}